// Round 1
// baseline (731.707 us; speedup 1.0000x reference)
//
#include <hip/hip_runtime.h>
#include <hip/hip_fp16.h>

#define TT 512
#define HH 128

typedef _Float16 half2_t __attribute__((ext_vector_type(2)));
typedef _Float16 half4_t __attribute__((ext_vector_type(4)));
typedef _Float16 half8_t __attribute__((ext_vector_type(8)));
typedef float    float4_t __attribute__((ext_vector_type(4)));

__device__ __forceinline__ half2_t h2(float v) {
    half2_t r; r[0] = (_Float16)v; r[1] = (_Float16)v; return r;
}
__device__ __forceinline__ half2_t pkrtz(float a, float b) {
    return __builtin_bit_cast(half2_t, __builtin_amdgcn_cvt_pkrtz(a, b));
}

// ---- packed-f16 polynomial activations (no transcendentals) ----
#define TC1 0.994940f
#define TC3 -0.290799f
#define TC5 0.065507f
#define TC7 -0.0062464f
#define SC1 0.2487350f
#define SC3 -0.0181749f
#define SC5 0.00102355f
#define SC7 -0.0000244141f

__device__ __forceinline__ half2_t tanh_pk(half2_t x) {
    half2_t m = __builtin_elementwise_min(__builtin_elementwise_max(x, h2(-2.0f)), h2(2.0f));
    half2_t t = m * m;
    half2_t p = h2(TC7) * t + h2(TC5);
    p = p * t + h2(TC3);
    p = p * t + h2(TC1);
    return m * p;
}
__device__ __forceinline__ half2_t sigma_pk(half2_t x) {
    half2_t m = __builtin_elementwise_min(__builtin_elementwise_max(x, h2(-4.0f)), h2(4.0f));
    half2_t t = m * m;
    half2_t p = h2(SC7) * t + h2(SC5);
    p = p * t + h2(SC3);
    p = p * t + h2(SC1);
    return m * p + h2(0.5f);
}

// LDS-only barrier: waits lgkmcnt(0), leaves global loads/stores in flight.
__device__ __forceinline__ void wg_barrier_lds() {
#if __has_builtin(__builtin_amdgcn_s_waitcnt)
    __builtin_amdgcn_s_waitcnt(0xC07F);   // lgkmcnt(0), vmcnt=max, expcnt=max
#else
    asm volatile("s_waitcnt lgkmcnt(0)" ::: "memory");
#endif
    __builtin_amdgcn_s_barrier();
}

// xp layout (f16): half index = (((dirbg*512 + t)*8 + w)*64 + lane)*16,
// 16 halfs per (t,w,lane) in D-order [T*4+r]. Transposed MFMA convention:
// lane (lq,lm) holds gates T*128 + w*16 + lq*4 + r for chain bg*16+lm.
__device__ __forceinline__ size_t xp_off(int dirbg, int t, int w, int lane) {
    return (((size_t)dirbg * 512 + t) * 8 + w) * 1024 + (size_t)lane * 16;
}

// ---- kernel 1: block-staged xp GEMM (r11, proven ~67us).
__global__ __attribute__((amdgpu_flat_work_group_size(512, 512), amdgpu_waves_per_eu(2, 2)))
void xp_gemm_kernel(
    const int* __restrict__ x, const float* __restrict__ emb,
    const float* __restrict__ Wih_f, const float* __restrict__ bih_f, const float* __restrict__ bhh_f,
    const float* __restrict__ Wih_b, const float* __restrict__ bih_b, const float* __restrict__ bhh_b,
    _Float16* __restrict__ xp)
{
    const int wg  = blockIdx.x;        // dirbg
    const int dir = wg >> 3, bg = wg & 7;
    const int tb  = blockIdx.y * 16;   // t-base

    const float* Wih = dir ? Wih_b : Wih_f;
    const float* bih = dir ? bih_b : bih_f;
    const float* bhh = dir ? bhh_b : bhh_f;

    const int tid = threadIdx.x;
    const int w = tid >> 6, lane = tid & 63, lq = lane >> 4, lm = lane & 15;

    __shared__ int id_sm[256];                 // [chain][t]
    __shared__ _Float16 Esm[256 * 136];        // [t*16+chain][col], +8 pad

    if (tid < 256)
        id_sm[tid] = x[(size_t)(bg * 16 + (tid >> 4)) * TT + tb + (tid & 15)];

    half8_t awih[4][4];
    #pragma unroll
    for (int T = 0; T < 4; ++T) {
        #pragma unroll
        for (int kk = 0; kk < 4; ++kk) {
            const float4* s = (const float4*)(Wih + (size_t)(T * 128 + w * 16 + lm) * 128 + kk * 32 + lq * 8);
            float4 v0 = s[0], v1 = s[1];
            half8_t h;
            half2_t a = pkrtz(v0.x, v0.y), b = pkrtz(v0.z, v0.w);
            half2_t c = pkrtz(v1.x, v1.y), d = pkrtz(v1.z, v1.w);
            h[0]=a[0]; h[1]=a[1]; h[2]=b[0]; h[3]=b[1];
            h[4]=c[0]; h[5]=c[1]; h[6]=d[0]; h[7]=d[1];
            awih[T][kk] = h;
        }
    }
    float4_t biasv[4];
    #pragma unroll
    for (int T = 0; T < 4; ++T) {
        int g = T * 128 + w * 16 + lq * 4;
        float4 b1 = *(const float4*)(bih + g);
        float4 b2 = *(const float4*)(bhh + g);
        biasv[T] = (float4_t){b1.x + b2.x, b1.y + b2.y, b1.z + b2.z, b1.w + b2.w};
    }
    __syncthreads();   // id_sm ready

    {   // stage phase: 2 threads per (chain,t) row, 16 float4 each
        const int r  = tid >> 1;
        const int hf = tid & 1;
        const int chain = r >> 4, tt2 = r & 15;
        const float* src = emb + (size_t)id_sm[r] * 128 + hf * 64;
        float4 v[16];
        #pragma unroll
        for (int j = 0; j < 16; ++j) v[j] = *(const float4*)(src + 4 * j);
        _Float16* dst = &Esm[(tt2 * 16 + chain) * 136 + hf * 64];
        #pragma unroll
        for (int j = 0; j < 16; ++j) {
            half2_t a = pkrtz(v[j].x, v[j].y), b = pkrtz(v[j].z, v[j].w);
            half4_t q; q[0]=a[0]; q[1]=a[1]; q[2]=b[0]; q[3]=b[1];
            *(half4_t*)(dst + 4 * j) = q;
        }
    }
    __syncthreads();   // Esm ready; read-only below -> no more barriers

    #pragma unroll 4
    for (int i = 0; i < 16; ++i) {
        half8_t bfr[4];
        #pragma unroll
        for (int kk = 0; kk < 4; ++kk)
            bfr[kk] = *(const half8_t*)&Esm[(i * 16 + lm) * 136 + kk * 32 + lq * 8];

        float4_t acc[4];
        #pragma unroll
        for (int T = 0; T < 4; ++T) acc[T] = biasv[T];
        #pragma unroll
        for (int kk = 0; kk < 4; ++kk)
            #pragma unroll
            for (int T = 0; T < 4; ++T)
                acc[T] = __builtin_amdgcn_mfma_f32_16x16x32_f16(awih[T][kk], bfr[kk], acc[T], 0, 0, 0);

        half8_t p0, p1;
        {
            half2_t a = pkrtz(acc[0][0], acc[0][1]), b = pkrtz(acc[0][2], acc[0][3]);
            half2_t c = pkrtz(acc[1][0], acc[1][1]), d = pkrtz(acc[1][2], acc[1][3]);
            p0[0]=a[0]; p0[1]=a[1]; p0[2]=b[0]; p0[3]=b[1];
            p0[4]=c[0]; p0[5]=c[1]; p0[6]=d[0]; p0[7]=d[1];
        }
        {
            half2_t a = pkrtz(acc[2][0], acc[2][1]), b = pkrtz(acc[2][2], acc[2][3]);
            half2_t c = pkrtz(acc[3][0], acc[3][1]), d = pkrtz(acc[3][2], acc[3][3]);
            p1[0]=a[0]; p1[1]=a[1]; p1[2]=b[0]; p1[3]=b[1];
            p1[4]=c[0]; p1[5]=c[1]; p1[6]=d[0]; p1[7]=d[1];
        }
        half8_t* dst = (half8_t*)(xp + xp_off(wg, tb + i, w, lane));
        dst[0] = p0; dst[1] = p1;
    }
}

// ---- kernel 2: recurrence. r12 change: merge BOTH directions of one batch
// group into a single 1024-thread block (16 waves, 4/SIMD). dir0 and dir1 are
// independent recurrences with identical per-step shape; interleaving their
// waves on each SIMD fills the lgkm/MFMA-latency/barrier stall windows that a
// 2-wave/SIMD lockstep block exposes. Grid: 8 blocks (one per bg).
__global__ __attribute__((amdgpu_flat_work_group_size(1024, 1024), amdgpu_waves_per_eu(4, 4)))
void bilstm_rec_kernel(
    const _Float16* __restrict__ xp,
    const float* __restrict__ Whh_f, const float* __restrict__ Whh_b,
    float* __restrict__ pooled)
{
    const int bg  = blockIdx.x;        // 0..7
    const int tid = threadIdx.x;
    const int w16 = tid >> 6;          // 0..15 wave id
    const int dir = w16 >> 3;          // waves 0-7: fwd, 8-15: bwd
    const int w   = w16 & 7;           // 0..7 gate-column group within dir
    const int lane = tid & 63, lq = lane >> 4, lm = lane & 15;
    const int wg  = dir * 8 + bg;      // dirbg for xp addressing

    const float* Whh = dir ? Whh_b : Whh_f;

    __shared__ _Float16 hsm[2][2][16 * 136];   // [dir][buf][chain][hdim], +8 pad

    half8_t awhh[4][4];
    #pragma unroll
    for (int T = 0; T < 4; ++T) {
        #pragma unroll
        for (int kk = 0; kk < 4; ++kk) {
            const float4* s = (const float4*)(Whh + (size_t)(T * 128 + w * 16 + lm) * 128 + kk * 32 + lq * 8);
            float4 v0 = s[0], v1 = s[1];
            half8_t h;
            half2_t a = pkrtz(v0.x, v0.y), b = pkrtz(v0.z, v0.w);
            half2_t c = pkrtz(v1.x, v1.y), d = pkrtz(v1.z, v1.w);
            h[0]=a[0]; h[1]=a[1]; h[2]=b[0]; h[3]=b[1];
            h[4]=c[0]; h[5]=c[1]; h[6]=d[0]; h[7]=d[1];
            awhh[T][kk] = h;
        }
    }

    for (int k = tid; k < 2 * 2 * 16 * 136; k += 1024)
        ((_Float16*)hsm)[k] = (_Float16)0.0f;

    const _Float16* xp_wl = xp + ((size_t)wg * 512 * 8 + w) * 1024 + (size_t)lane * 16;

    half8_t Qa[4], Qb[4];
    {
        int ta = dir ? (TT - 1) : 0;
        const half8_t* p = (const half8_t*)(xp_wl + (size_t)ta * 8192);
        Qa[0] = p[0]; Qb[0] = p[1];
    }
    {
        int ta = dir ? (TT - 2) : 1;
        const half8_t* p = (const half8_t*)(xp_wl + (size_t)ta * 8192);
        Qa[1] = p[0]; Qb[1] = p[1];
    }
    __syncthreads();

    const float4_t zz = {0.0f, 0.0f, 0.0f, 0.0f};   // persistent zero C-input
    half2_t c01 = h2(0.0f), c23 = h2(0.0f);
    half2_t hm01 = h2(-60000.0f), hm23 = h2(-60000.0f);

    for (int tbs = 0; tbs < TT; tbs += 4) {
        #pragma unroll
        for (int P = 0; P < 4; ++P) {
            const int t = tbs + P;
            {   // prefetch xp(t+2) into buffer (P+2)&3
                int tl = (t + 2 < TT) ? (t + 2) : (TT - 1);
                int ta = dir ? (TT - 1 - tl) : tl;
                const half8_t* pp = (const half8_t*)(xp_wl + (size_t)ta * 8192);
                Qa[(P + 2) & 3] = pp[0]; Qb[(P + 2) & 3] = pp[1];
            }

            half8_t bh[4];
            #pragma unroll
            for (int kk = 0; kk < 4; ++kk)
                bh[kk] = *(const half8_t*)&hsm[dir][P & 1][lm * 136 + kk * 32 + lq * 8];

            // MFMA from zero-C; xp added post-MFMA in f16
            float4_t acc[4];
            #pragma unroll
            for (int T = 0; T < 4; ++T)
                acc[T] = __builtin_amdgcn_mfma_f32_16x16x32_f16(awhh[T][0], bh[0], zz, 0, 0, 0);
            #pragma unroll
            for (int kk = 1; kk < 4; ++kk)
                #pragma unroll
                for (int T = 0; T < 4; ++T)
                    acc[T] = __builtin_amdgcn_mfma_f32_16x16x32_f16(awhh[T][kk], bh[kk], acc[T], 0, 0, 0);

            // xp half2 views (alias Q's VGPRs; no conversion instructions)
            half2_t qa0 = __builtin_shufflevector(Qa[P], Qa[P], 0, 1);
            half2_t qa1 = __builtin_shufflevector(Qa[P], Qa[P], 2, 3);
            half2_t qa2 = __builtin_shufflevector(Qa[P], Qa[P], 4, 5);
            half2_t qa3 = __builtin_shufflevector(Qa[P], Qa[P], 6, 7);
            half2_t qb0 = __builtin_shufflevector(Qb[P], Qb[P], 0, 1);
            half2_t qb1 = __builtin_shufflevector(Qb[P], Qb[P], 2, 3);
            half2_t qb2 = __builtin_shufflevector(Qb[P], Qb[P], 4, 5);
            half2_t qb3 = __builtin_shufflevector(Qb[P], Qb[P], 6, 7);

            half2_t i01 = sigma_pk(pkrtz(acc[0][0], acc[0][1]) + qa0);
            half2_t i23 = sigma_pk(pkrtz(acc[0][2], acc[0][3]) + qa1);
            half2_t f01 = sigma_pk(pkrtz(acc[1][0], acc[1][1]) + qa2);
            half2_t f23 = sigma_pk(pkrtz(acc[1][2], acc[1][3]) + qa3);
            half2_t g01 = tanh_pk(pkrtz(acc[2][0], acc[2][1]) + qb0);
            half2_t g23 = tanh_pk(pkrtz(acc[2][2], acc[2][3]) + qb1);
            half2_t o01 = sigma_pk(pkrtz(acc[3][0], acc[3][1]) + qb2);
            half2_t o23 = sigma_pk(pkrtz(acc[3][2], acc[3][3]) + qb3);

            c01 = f01 * c01 + i01 * g01;
            c23 = f23 * c23 + i23 * g23;
            half2_t h01 = o01 * tanh_pk(c01);
            half2_t h23 = o23 * tanh_pk(c23);
            hm01 = __builtin_elementwise_max(hm01, h01);
            hm23 = __builtin_elementwise_max(hm23, h23);

            half4_t hv4;
            hv4[0] = h01[0]; hv4[1] = h01[1]; hv4[2] = h23[0]; hv4[3] = h23[1];
            *(half4_t*)&hsm[dir][1 - (P & 1)][lm * 136 + w * 16 + lq * 4] = hv4;

            wg_barrier_lds();
        }
    }

    float4 o;
    o.x = (float)hm01[0]; o.y = (float)hm01[1];
    o.z = (float)hm23[0]; o.w = (float)hm23[1];
    *(float4*)&pooled[(size_t)(bg * 16 + lm) * 256 + dir * HH + w * 16 + lq * 4] = o;
}

// ---- kernel 3: pooled (128,256) -> relu(W1·+b1) -> sigmoid(W2·+b2) -> (128,1)
__global__ __launch_bounds__(64) void mlp_kernel(
    const float* __restrict__ pooled, const float* __restrict__ W1,
    const float* __restrict__ b1, const float* __restrict__ W2,
    const float* __restrict__ b2, float* __restrict__ out)
{
    const int b = blockIdx.x;
    const int j = threadIdx.x;
    const float4* p = (const float4*)(pooled + (size_t)b * 256);
    const float4* wv = (const float4*)(W1 + (size_t)j * 256);
    float s = 0.0f;
    #pragma unroll
    for (int q = 0; q < 64; ++q) {
        float4 pv = p[q];
        float4 ww = wv[q];
        s += pv.x * ww.x + pv.y * ww.y + pv.z * ww.z + pv.w * ww.w;
    }
    s += b1[j];
    s = fmaxf(s, 0.0f);
    float v = W2[j] * s;
    #pragma unroll
    for (int off = 32; off; off >>= 1) v += __shfl_down(v, off);
    if (j == 0) out[b] = 1.0f / (1.0f + __expf(-(v + b2[0])));
}

extern "C" void kernel_launch(void* const* d_in, const int* in_sizes, int n_in,
                              void* d_out, int out_size, void* d_ws, size_t ws_size,
                              hipStream_t stream) {
    const int*   x     = (const int*)d_in[0];
    const float* emb   = (const float*)d_in[1];
    const float* Wih_f = (const float*)d_in[2];
    const float* Whh_f = (const float*)d_in[3];
    const float* bih_f = (const float*)d_in[4];
    const float* bhh_f = (const float*)d_in[5];
    const float* Wih_b = (const float*)d_in[6];
    const float* Whh_b = (const float*)d_in[7];
    const float* bih_b = (const float*)d_in[8];
    const float* bhh_b = (const float*)d_in[9];
    const float* W1    = (const float*)d_in[10];
    const float* b1    = (const float*)d_in[11];
    const float* W2    = (const float*)d_in[12];
    const float* b2    = (const float*)d_in[13];
    float* out = (float*)d_out;

    char* ws = (char*)d_ws;
    float*    pooled = (float*)ws;                 // 128 KB
    _Float16* xp     = (_Float16*)(ws + 131072);   // 134.2 MB

    hipLaunchKernelGGL(xp_gemm_kernel, dim3(16, 32), dim3(512), 0, stream,
                       x, emb, Wih_f, bih_f, bhh_f, Wih_b, bih_b, bhh_b, xp);
    hipLaunchKernelGGL(bilstm_rec_kernel, dim3(8), dim3(1024), 0, stream,
                       xp, Whh_f, Whh_b, pooled);
    hipLaunchKernelGGL(mlp_kernel, dim3(128), dim3(64), 0, stream,
                       pooled, W1, b1, W2, b2, out);
}

// Round 2
// 583.025 us; speedup vs baseline: 1.2550x; 1.2550x over previous
//
#include <hip/hip_runtime.h>
#include <hip/hip_fp16.h>

#define TT 512
#define HH 128

typedef _Float16 half2_t __attribute__((ext_vector_type(2)));
typedef _Float16 half4_t __attribute__((ext_vector_type(4)));
typedef _Float16 half8_t __attribute__((ext_vector_type(8)));
typedef float    float4_t __attribute__((ext_vector_type(4)));

__device__ __forceinline__ half2_t h2(float v) {
    half2_t r; r[0] = (_Float16)v; r[1] = (_Float16)v; return r;
}
__device__ __forceinline__ half2_t pkrtz(float a, float b) {
    return __builtin_bit_cast(half2_t, __builtin_amdgcn_cvt_pkrtz(a, b));
}

// ---- packed-f16 polynomial activations (no transcendentals) ----
#define TC1 0.994940f
#define TC3 -0.290799f
#define TC5 0.065507f
#define TC7 -0.0062464f
#define SC1 0.2487350f
#define SC3 -0.0181749f
#define SC5 0.00102355f
#define SC7 -0.0000244141f

__device__ __forceinline__ half2_t tanh_pk(half2_t x) {
    half2_t m = __builtin_elementwise_min(__builtin_elementwise_max(x, h2(-2.0f)), h2(2.0f));
    half2_t t = m * m;
    half2_t p = h2(TC7) * t + h2(TC5);
    p = p * t + h2(TC3);
    p = p * t + h2(TC1);
    return m * p;
}
__device__ __forceinline__ half2_t sigma_pk(half2_t x) {
    half2_t m = __builtin_elementwise_min(__builtin_elementwise_max(x, h2(-4.0f)), h2(4.0f));
    half2_t t = m * m;
    half2_t p = h2(SC7) * t + h2(SC5);
    p = p * t + h2(SC3);
    p = p * t + h2(SC1);
    return m * p + h2(0.5f);
}

// LDS-only barrier: waits lgkmcnt(0), leaves global loads in flight.
__device__ __forceinline__ void wg_barrier_lds() {
#if __has_builtin(__builtin_amdgcn_s_waitcnt)
    __builtin_amdgcn_s_waitcnt(0xC07F);   // lgkmcnt(0), vmcnt=max, expcnt=max
#else
    asm volatile("s_waitcnt lgkmcnt(0)" ::: "memory");
#endif
    __builtin_amdgcn_s_barrier();
}

// ---- fused kernel: embedding gather + xp GEMM + recurrence, one pass.
// Per step t (one barrier/step, r10-proven sync structure):
//   gates(t) = MFMA(Whh, h(t-1), C = xp(t))   [xp(t) built during step t-1]
//   xp(t+1)  = MFMA(Wih, e(t+1), C = bias)    [independent of h -> fills stalls]
//   stage e(t+2): gather 16 emb rows -> f16 LDS tile (full-step latency cover)
// Grid: 16 blocks (dirbg), 512 threads, 2 waves/EU.
__global__ __attribute__((amdgpu_flat_work_group_size(512, 512), amdgpu_waves_per_eu(2, 2)))
void bilstm_fused_kernel(
    const int* __restrict__ x, const float* __restrict__ emb,
    const float* __restrict__ Wih_f, const float* __restrict__ bih_f, const float* __restrict__ bhh_f,
    const float* __restrict__ Wih_b, const float* __restrict__ bih_b, const float* __restrict__ bhh_b,
    const float* __restrict__ Whh_f, const float* __restrict__ Whh_b,
    float* __restrict__ pooled)
{
    const int wg  = blockIdx.x;        // 0..15 dirbg
    const int dir = wg >> 3, bg = wg & 7;
    const float* Wih = dir ? Wih_b : Wih_f;
    const float* bih = dir ? bih_b : bih_f;
    const float* bhh = dir ? bhh_b : bhh_f;
    const float* Whh = dir ? Whh_b : Whh_f;

    const int tid = threadIdx.x;
    const int w = tid >> 6, lane = tid & 63, lq = lane >> 4, lm = lane & 15;
    const int srow = tid >> 5, sslot = tid & 31;   // staging: row 0..15, slot 0..31

    __shared__ int x_sm[16 * 512];               // 32 KB: this block's token ids
    __shared__ _Float16 esm[2][16 * 136];        // 8.5 KB: emb tiles [chain][col], +8 pad
    __shared__ _Float16 hsm[2][16 * 136];        // 8.5 KB: h tiles  [chain][hdim], +8 pad

    // ---- weight fragments (A-operands), verbatim r10/r11 layout ----
    half8_t awih[4][4], awhh[4][4];
    #pragma unroll
    for (int T = 0; T < 4; ++T) {
        #pragma unroll
        for (int kk = 0; kk < 4; ++kk) {
            const float4* s1 = (const float4*)(Wih + (size_t)(T * 128 + w * 16 + lm) * 128 + kk * 32 + lq * 8);
            float4 v0 = s1[0], v1 = s1[1];
            half8_t h;
            half2_t a = pkrtz(v0.x, v0.y), b = pkrtz(v0.z, v0.w);
            half2_t c = pkrtz(v1.x, v1.y), d = pkrtz(v1.z, v1.w);
            h[0]=a[0]; h[1]=a[1]; h[2]=b[0]; h[3]=b[1];
            h[4]=c[0]; h[5]=c[1]; h[6]=d[0]; h[7]=d[1];
            awih[T][kk] = h;
            const float4* s2 = (const float4*)(Whh + (size_t)(T * 128 + w * 16 + lm) * 128 + kk * 32 + lq * 8);
            float4 u0 = s2[0], u1 = s2[1];
            half8_t g;
            half2_t e = pkrtz(u0.x, u0.y), f = pkrtz(u0.z, u0.w);
            half2_t gg = pkrtz(u1.x, u1.y), hh = pkrtz(u1.z, u1.w);
            g[0]=e[0]; g[1]=e[1]; g[2]=f[0]; g[3]=f[1];
            g[4]=gg[0]; g[5]=gg[1]; g[6]=hh[0]; g[7]=hh[1];
            awhh[T][kk] = g;
        }
    }
    float4_t biasv[4];
    #pragma unroll
    for (int T = 0; T < 4; ++T) {
        int g = T * 128 + w * 16 + lq * 4;
        float4 b1 = *(const float4*)(bih + g);
        float4 b2 = *(const float4*)(bhh + g);
        biasv[T] = (float4_t){b1.x + b2.x, b1.y + b2.y, b1.z + b2.z, b1.w + b2.w};
    }

    // token ids for this block's 16 chains (coalesced copy)
    for (int k = tid; k < 16 * 512; k += 512)
        x_sm[k] = x[(size_t)(bg * 16 + (k >> 9)) * TT + (k & 511)];
    // h(-1) = 0
    for (int k = tid; k < 2 * 16 * 136; k += 512)
        ((_Float16*)hsm)[k] = (_Float16)0.0f;
    __syncthreads();   // x_sm ready

    // ---- prologue: stage e(0) -> buf0, e(1) -> buf1 ----
    {
        int t0 = dir ? (TT - 1) : 0;
        int t1 = dir ? (TT - 2) : 1;
        int i0 = x_sm[srow * 512 + t0];
        int i1 = x_sm[srow * 512 + t1];
        float4 v0 = *(const float4*)(emb + (size_t)i0 * 128 + sslot * 4);
        float4 v1 = *(const float4*)(emb + (size_t)i1 * 128 + sslot * 4);
        half2_t a0 = pkrtz(v0.x, v0.y), b0 = pkrtz(v0.z, v0.w);
        half4_t q0; q0[0]=a0[0]; q0[1]=a0[1]; q0[2]=b0[0]; q0[3]=b0[1];
        *(half4_t*)&esm[0][srow * 136 + sslot * 4] = q0;
        half2_t a1 = pkrtz(v1.x, v1.y), b1 = pkrtz(v1.z, v1.w);
        half4_t q1; q1[0]=a1[0]; q1[1]=a1[1]; q1[2]=b1[0]; q1[3]=b1[1];
        *(half4_t*)&esm[1][srow * 136 + sslot * 4] = q1;
    }
    __syncthreads();   // esm[0], esm[1] ready

    // xpA = bias + Wih·e(0)
    float4_t xpA[4], xpB[4];
    {
        half8_t be[4];
        #pragma unroll
        for (int kk = 0; kk < 4; ++kk)
            be[kk] = *(const half8_t*)&esm[0][lm * 136 + kk * 32 + lq * 8];
        #pragma unroll
        for (int T = 0; T < 4; ++T) xpA[T] = biasv[T];
        #pragma unroll
        for (int kk = 0; kk < 4; ++kk)
            #pragma unroll
            for (int T = 0; T < 4; ++T)
                xpA[T] = __builtin_amdgcn_mfma_f32_16x16x32_f16(awih[T][kk], be[kk], xpA[T], 0, 0, 0);
    }
    wg_barrier_lds();  // esm[0] reads done before step-0 overwrites it

    half2_t c01 = h2(0.0f), c23 = h2(0.0f);
    half2_t hm01 = h2(-60000.0f), hm23 = h2(-60000.0f);

    // One step: gates from XPIN, build XPOUT = xp(t+1), stage e(t+2).
    #define FSTEP(T_, XPIN, XPOUT) do {                                             \
        const int t_ = (T_);                                                        \
        /* 1. h(t-1) reads (critical path head) */                                  \
        half8_t bh[4];                                                              \
        _Pragma("unroll")                                                           \
        for (int kk = 0; kk < 4; ++kk)                                              \
            bh[kk] = *(const half8_t*)&hsm[t_ & 1][lm * 136 + kk * 32 + lq * 8];    \
        /* 2. issue gather for e(t+2) early (consumed end of step) */               \
        int k2 = (t_ + 2 < TT) ? (t_ + 2) : (TT - 1);                               \
        int tau = dir ? (TT - 1 - k2) : k2;                                         \
        int idxv = x_sm[srow * 512 + tau];                                          \
        float4 ev = *(const float4*)(emb + (size_t)idxv * 128 + sslot * 4);         \
        /* 3. e(t+1) reads */                                                       \
        half8_t be[4];                                                              \
        _Pragma("unroll")                                                           \
        for (int kk = 0; kk < 4; ++kk)                                              \
            be[kk] = *(const half8_t*)&esm[(t_ + 1) & 1][lm * 136 + kk * 32 + lq * 8]; \
        /* 4. recurrence MFMA, C = xp(t) */                                         \
        float4_t acc[4];                                                            \
        _Pragma("unroll")                                                           \
        for (int T = 0; T < 4; ++T)                                                 \
            acc[T] = __builtin_amdgcn_mfma_f32_16x16x32_f16(awhh[T][0], bh[0], XPIN[T], 0, 0, 0); \
        _Pragma("unroll")                                                           \
        for (int kk = 1; kk < 4; ++kk)                                              \
            _Pragma("unroll")                                                       \
            for (int T = 0; T < 4; ++T)                                             \
                acc[T] = __builtin_amdgcn_mfma_f32_16x16x32_f16(awhh[T][kk], bh[kk], acc[T], 0, 0, 0); \
        /* 5. xp(t+1) MFMA, independent of h -> fills stall windows */              \
        _Pragma("unroll")                                                           \
        for (int T = 0; T < 4; ++T)                                                 \
            XPOUT[T] = __builtin_amdgcn_mfma_f32_16x16x32_f16(awih[T][0], be[0], biasv[T], 0, 0, 0); \
        _Pragma("unroll")                                                           \
        for (int kk = 1; kk < 4; ++kk)                                              \
            _Pragma("unroll")                                                       \
            for (int T = 0; T < 4; ++T)                                             \
                XPOUT[T] = __builtin_amdgcn_mfma_f32_16x16x32_f16(awih[T][kk], be[kk], XPOUT[T], 0, 0, 0); \
        /* 6. activations (gates already include xp in f32) */                      \
        half2_t i01 = sigma_pk(pkrtz(acc[0][0], acc[0][1]));                        \
        half2_t i23 = sigma_pk(pkrtz(acc[0][2], acc[0][3]));                        \
        half2_t f01 = sigma_pk(pkrtz(acc[1][0], acc[1][1]));                        \
        half2_t f23 = sigma_pk(pkrtz(acc[1][2], acc[1][3]));                        \
        half2_t g01 = tanh_pk(pkrtz(acc[2][0], acc[2][1]));                         \
        half2_t g23 = tanh_pk(pkrtz(acc[2][2], acc[2][3]));                         \
        half2_t o01 = sigma_pk(pkrtz(acc[3][0], acc[3][1]));                        \
        half2_t o23 = sigma_pk(pkrtz(acc[3][2], acc[3][3]));                        \
        c01 = f01 * c01 + i01 * g01;                                                \
        c23 = f23 * c23 + i23 * g23;                                                \
        half2_t h01 = o01 * tanh_pk(c01);                                           \
        half2_t h23 = o23 * tanh_pk(c23);                                           \
        hm01 = __builtin_elementwise_max(hm01, h01);                                \
        hm23 = __builtin_elementwise_max(hm23, h23);                                \
        half4_t hv4;                                                                \
        hv4[0] = h01[0]; hv4[1] = h01[1]; hv4[2] = h23[0]; hv4[3] = h23[1];         \
        *(half4_t*)&hsm[1 - (t_ & 1)][lm * 136 + w * 16 + lq * 4] = hv4;            \
        /* 7. stage e(t+2) -> esm[t&1] (buffer consumed at step t-1) */             \
        half2_t sa = pkrtz(ev.x, ev.y), sb = pkrtz(ev.z, ev.w);                     \
        half4_t sq; sq[0]=sa[0]; sq[1]=sa[1]; sq[2]=sb[0]; sq[3]=sb[1];             \
        *(half4_t*)&esm[t_ & 1][srow * 136 + sslot * 4] = sq;                       \
        wg_barrier_lds();                                                           \
    } while (0)

    #pragma unroll 1
    for (int t = 0; t < TT; t += 2) {
        FSTEP(t,     xpA, xpB);
        FSTEP(t + 1, xpB, xpA);
    }
    #undef FSTEP

    float4 o;
    o.x = (float)hm01[0]; o.y = (float)hm01[1];
    o.z = (float)hm23[0]; o.w = (float)hm23[1];
    *(float4*)&pooled[(size_t)(bg * 16 + lm) * 256 + dir * HH + w * 16 + lq * 4] = o;
}

// ---- kernel 3: pooled (128,256) -> relu(W1·+b1) -> sigmoid(W2·+b2) -> (128,1)
__global__ __launch_bounds__(64) void mlp_kernel(
    const float* __restrict__ pooled, const float* __restrict__ W1,
    const float* __restrict__ b1, const float* __restrict__ W2,
    const float* __restrict__ b2, float* __restrict__ out)
{
    const int b = blockIdx.x;
    const int j = threadIdx.x;
    const float4* p = (const float4*)(pooled + (size_t)b * 256);
    const float4* wv = (const float4*)(W1 + (size_t)j * 256);
    float s = 0.0f;
    #pragma unroll
    for (int q = 0; q < 64; ++q) {
        float4 pv = p[q];
        float4 ww = wv[q];
        s += pv.x * ww.x + pv.y * ww.y + pv.z * ww.z + pv.w * ww.w;
    }
    s += b1[j];
    s = fmaxf(s, 0.0f);
    float v = W2[j] * s;
    #pragma unroll
    for (int off = 32; off; off >>= 1) v += __shfl_down(v, off);
    if (j == 0) out[b] = 1.0f / (1.0f + __expf(-(v + b2[0])));
}

extern "C" void kernel_launch(void* const* d_in, const int* in_sizes, int n_in,
                              void* d_out, int out_size, void* d_ws, size_t ws_size,
                              hipStream_t stream) {
    const int*   x     = (const int*)d_in[0];
    const float* emb   = (const float*)d_in[1];
    const float* Wih_f = (const float*)d_in[2];
    const float* Whh_f = (const float*)d_in[3];
    const float* bih_f = (const float*)d_in[4];
    const float* bhh_f = (const float*)d_in[5];
    const float* Wih_b = (const float*)d_in[6];
    const float* Whh_b = (const float*)d_in[7];
    const float* bih_b = (const float*)d_in[8];
    const float* bhh_b = (const float*)d_in[9];
    const float* W1    = (const float*)d_in[10];
    const float* b1    = (const float*)d_in[11];
    const float* W2    = (const float*)d_in[12];
    const float* b2    = (const float*)d_in[13];
    float* out = (float*)d_out;

    float* pooled = (float*)d_ws;   // 128 KB

    hipLaunchKernelGGL(bilstm_fused_kernel, dim3(16), dim3(512), 0, stream,
                       x, emb, Wih_f, bih_f, bhh_f, Wih_b, bih_b, bhh_b,
                       Whh_f, Whh_b, pooled);
    hipLaunchKernelGGL(mlp_kernel, dim3(128), dim3(64), 0, stream,
                       pooled, W1, b1, W2, b2, out);
}

// Round 3
// 561.245 us; speedup vs baseline: 1.3037x; 1.0388x over previous
//
#include <hip/hip_runtime.h>
#include <hip/hip_fp16.h>

#define TT 512
#define HH 128

typedef _Float16 half2_t __attribute__((ext_vector_type(2)));
typedef _Float16 half4_t __attribute__((ext_vector_type(4)));
typedef _Float16 half8_t __attribute__((ext_vector_type(8)));
typedef float    float4_t __attribute__((ext_vector_type(4)));

__device__ __forceinline__ half2_t h2(float v) {
    half2_t r; r[0] = (_Float16)v; r[1] = (_Float16)v; return r;
}
__device__ __forceinline__ half2_t pkrtz(float a, float b) {
    return __builtin_bit_cast(half2_t, __builtin_amdgcn_cvt_pkrtz(a, b));
}

// ---- packed-f16 polynomial activations (no transcendentals) ----
#define TC1 0.994940f
#define TC3 -0.290799f
#define TC5 0.065507f
#define TC7 -0.0062464f
#define SC1 0.2487350f
#define SC3 -0.0181749f
#define SC5 0.00102355f
#define SC7 -0.0000244141f

__device__ __forceinline__ half2_t tanh_pk(half2_t x) {
    half2_t m = __builtin_elementwise_min(__builtin_elementwise_max(x, h2(-2.0f)), h2(2.0f));
    half2_t t = m * m;
    half2_t p = h2(TC7) * t + h2(TC5);
    p = p * t + h2(TC3);
    p = p * t + h2(TC1);
    return m * p;
}
__device__ __forceinline__ half2_t sigma_pk(half2_t x) {
    half2_t m = __builtin_elementwise_min(__builtin_elementwise_max(x, h2(-4.0f)), h2(4.0f));
    half2_t t = m * m;
    half2_t p = h2(SC7) * t + h2(SC5);
    p = p * t + h2(SC3);
    p = p * t + h2(SC1);
    return m * p + h2(0.5f);
}

// LDS-only barrier: waits lgkmcnt(0), leaves global loads in flight.
__device__ __forceinline__ void wg_barrier_lds() {
#if __has_builtin(__builtin_amdgcn_s_waitcnt)
    __builtin_amdgcn_s_waitcnt(0xC07F);   // lgkmcnt(0), vmcnt=max, expcnt=max
#else
    asm volatile("s_waitcnt lgkmcnt(0)" ::: "memory");
#endif
    __builtin_amdgcn_s_barrier();
}

// xp layout (f16): half index = (((dirbg*512 + t)*8 + w)*1024 + lane*16,
// 16 halfs per (t,w,lane) in D-order [T*4+r]. Transposed MFMA convention:
// lane (lq,lm) holds gates T*128 + w*16 + lq*4 + r for chain bg*16+lm.
__device__ __forceinline__ size_t xp_off(int dirbg, int t, int w, int lane) {
    return (((size_t)dirbg * 512 + t) * 8 + w) * 1024 + (size_t)lane * 16;
}

// ---- kernel 1: block-staged xp GEMM (r11, proven ~67us). Unchanged.
__global__ __attribute__((amdgpu_flat_work_group_size(512, 512), amdgpu_waves_per_eu(2, 2)))
void xp_gemm_kernel(
    const int* __restrict__ x, const float* __restrict__ emb,
    const float* __restrict__ Wih_f, const float* __restrict__ bih_f, const float* __restrict__ bhh_f,
    const float* __restrict__ Wih_b, const float* __restrict__ bih_b, const float* __restrict__ bhh_b,
    _Float16* __restrict__ xp)
{
    const int wg  = blockIdx.x;        // dirbg
    const int dir = wg >> 3, bg = wg & 7;
    const int tb  = blockIdx.y * 16;   // t-base

    const float* Wih = dir ? Wih_b : Wih_f;
    const float* bih = dir ? bih_b : bih_f;
    const float* bhh = dir ? bhh_b : bhh_f;

    const int tid = threadIdx.x;
    const int w = tid >> 6, lane = tid & 63, lq = lane >> 4, lm = lane & 15;

    __shared__ int id_sm[256];                 // [chain][t]
    __shared__ _Float16 Esm[256 * 136];        // [t*16+chain][col], +8 pad

    if (tid < 256)
        id_sm[tid] = x[(size_t)(bg * 16 + (tid >> 4)) * TT + tb + (tid & 15)];

    half8_t awih[4][4];
    #pragma unroll
    for (int T = 0; T < 4; ++T) {
        #pragma unroll
        for (int kk = 0; kk < 4; ++kk) {
            const float4* s = (const float4*)(Wih + (size_t)(T * 128 + w * 16 + lm) * 128 + kk * 32 + lq * 8);
            float4 v0 = s[0], v1 = s[1];
            half8_t h;
            half2_t a = pkrtz(v0.x, v0.y), b = pkrtz(v0.z, v0.w);
            half2_t c = pkrtz(v1.x, v1.y), d = pkrtz(v1.z, v1.w);
            h[0]=a[0]; h[1]=a[1]; h[2]=b[0]; h[3]=b[1];
            h[4]=c[0]; h[5]=c[1]; h[6]=d[0]; h[7]=d[1];
            awih[T][kk] = h;
        }
    }
    float4_t biasv[4];
    #pragma unroll
    for (int T = 0; T < 4; ++T) {
        int g = T * 128 + w * 16 + lq * 4;
        float4 b1 = *(const float4*)(bih + g);
        float4 b2 = *(const float4*)(bhh + g);
        biasv[T] = (float4_t){b1.x + b2.x, b1.y + b2.y, b1.z + b2.z, b1.w + b2.w};
    }
    __syncthreads();   // id_sm ready

    {   // stage phase: 2 threads per (chain,t) row, 16 float4 each
        const int r  = tid >> 1;
        const int hf = tid & 1;
        const int chain = r >> 4, tt2 = r & 15;
        const float* src = emb + (size_t)id_sm[r] * 128 + hf * 64;
        float4 v[16];
        #pragma unroll
        for (int j = 0; j < 16; ++j) v[j] = *(const float4*)(src + 4 * j);
        _Float16* dst = &Esm[(tt2 * 16 + chain) * 136 + hf * 64];
        #pragma unroll
        for (int j = 0; j < 16; ++j) {
            half2_t a = pkrtz(v[j].x, v[j].y), b = pkrtz(v[j].z, v[j].w);
            half4_t q; q[0]=a[0]; q[1]=a[1]; q[2]=b[0]; q[3]=b[1];
            *(half4_t*)(dst + 4 * j) = q;
        }
    }
    __syncthreads();   // Esm ready; read-only below -> no more barriers

    #pragma unroll 4
    for (int i = 0; i < 16; ++i) {
        half8_t bfr[4];
        #pragma unroll
        for (int kk = 0; kk < 4; ++kk)
            bfr[kk] = *(const half8_t*)&Esm[(i * 16 + lm) * 136 + kk * 32 + lq * 8];

        float4_t acc[4];
        #pragma unroll
        for (int T = 0; T < 4; ++T) acc[T] = biasv[T];
        #pragma unroll
        for (int kk = 0; kk < 4; ++kk)
            #pragma unroll
            for (int T = 0; T < 4; ++T)
                acc[T] = __builtin_amdgcn_mfma_f32_16x16x32_f16(awih[T][kk], bfr[kk], acc[T], 0, 0, 0);

        half8_t p0, p1;
        {
            half2_t a = pkrtz(acc[0][0], acc[0][1]), b = pkrtz(acc[0][2], acc[0][3]);
            half2_t c = pkrtz(acc[1][0], acc[1][1]), d = pkrtz(acc[1][2], acc[1][3]);
            p0[0]=a[0]; p0[1]=a[1]; p0[2]=b[0]; p0[3]=b[1];
            p0[4]=c[0]; p0[5]=c[1]; p0[6]=d[0]; p0[7]=d[1];
        }
        {
            half2_t a = pkrtz(acc[2][0], acc[2][1]), b = pkrtz(acc[2][2], acc[2][3]);
            half2_t c = pkrtz(acc[3][0], acc[3][1]), d = pkrtz(acc[3][2], acc[3][3]);
            p1[0]=a[0]; p1[1]=a[1]; p1[2]=b[0]; p1[3]=b[1];
            p1[4]=c[0]; p1[5]=c[1]; p1[6]=d[0]; p1[7]=d[1];
        }
        half8_t* dst = (half8_t*)(xp + xp_off(wg, tb + i, w, lane));
        dst[0] = p0; dst[1] = p1;
    }
}

// ---- kernel 2: recurrence, r14: 4 waves x 32 MFMAs (was 8 x 16).
// B-fragment (h tile) LDS reads are replicated once PER WAVE; halving the
// wave count halves the per-CU LDS pipe queue that sits on the critical
// path after each barrier. Each wave now owns old column-groups (2wv, 2wv+1):
// double weight frags (awhh[4][2][4] = 128 VGPR), double xp loads, double
// activation state. 1 wave/SIMD, waves_per_eu(1,1) -> 512-VGPR budget.
__global__ __attribute__((amdgpu_flat_work_group_size(256, 256), amdgpu_waves_per_eu(1, 1)))
void bilstm_rec_kernel(
    const _Float16* __restrict__ xp,
    const float* __restrict__ Whh_f, const float* __restrict__ Whh_b,
    float* __restrict__ pooled)
{
    const int wg  = blockIdx.x;        // 0..15 dirbg
    const int dir = wg >> 3, bg = wg & 7;
    const float* Whh = dir ? Whh_b : Whh_f;

    const int tid = threadIdx.x;
    const int wv = tid >> 6;           // 0..3 wave
    const int lane = tid & 63, lq = lane >> 4, lm = lane & 15;

    __shared__ _Float16 hsm[2][16 * 136];   // [buf][chain][hdim], +8 halfs pad

    // A-fragments: gate T (0..3 = i,f,g,o), parity p -> rows T*128+(2wv+p)*16
    half8_t awhh[4][2][4];
    #pragma unroll
    for (int T = 0; T < 4; ++T)
        #pragma unroll
        for (int p = 0; p < 2; ++p)
            #pragma unroll
            for (int kk = 0; kk < 4; ++kk) {
                const float4* s = (const float4*)(Whh + (size_t)(T * 128 + (2 * wv + p) * 16 + lm) * 128 + kk * 32 + lq * 8);
                float4 v0 = s[0], v1 = s[1];
                half8_t h;
                half2_t a = pkrtz(v0.x, v0.y), b = pkrtz(v0.z, v0.w);
                half2_t c = pkrtz(v1.x, v1.y), d = pkrtz(v1.z, v1.w);
                h[0]=a[0]; h[1]=a[1]; h[2]=b[0]; h[3]=b[1];
                h[4]=c[0]; h[5]=c[1]; h[6]=d[0]; h[7]=d[1];
                awhh[T][p][kk] = h;
            }

    for (int k = tid; k < 2 * 16 * 136; k += 256)
        ((_Float16*)hsm)[k] = (_Float16)0.0f;

    // xp pointers for both parities (old-w = 2wv, 2wv+1)
    const _Float16* xq0 = xp + ((size_t)wg * 512 * 8 + 2 * wv) * 1024 + (size_t)lane * 16;
    const _Float16* xq1 = xq0 + 1024;

    // Q[buf][p*2+j]: 4 rotating buffers, 2-step lookahead, 4 half8/step
    half8_t Q[4][4];
    {
        int ta = dir ? (TT - 1) : 0;
        const half8_t* p0 = (const half8_t*)(xq0 + (size_t)ta * 8192);
        const half8_t* p1 = (const half8_t*)(xq1 + (size_t)ta * 8192);
        Q[0][0] = p0[0]; Q[0][1] = p0[1]; Q[0][2] = p1[0]; Q[0][3] = p1[1];
    }
    {
        int ta = dir ? (TT - 2) : 1;
        const half8_t* p0 = (const half8_t*)(xq0 + (size_t)ta * 8192);
        const half8_t* p1 = (const half8_t*)(xq1 + (size_t)ta * 8192);
        Q[1][0] = p0[0]; Q[1][1] = p0[1]; Q[1][2] = p1[0]; Q[1][3] = p1[1];
    }
    __syncthreads();

    const float4_t zz = {0.0f, 0.0f, 0.0f, 0.0f};
    half2_t c01[2], c23[2], hm01[2], hm23[2];
    #pragma unroll
    for (int p = 0; p < 2; ++p) {
        c01[p] = h2(0.0f); c23[p] = h2(0.0f);
        hm01[p] = h2(-60000.0f); hm23[p] = h2(-60000.0f);
    }

    for (int tbs = 0; tbs < TT; tbs += 4) {
        #pragma unroll
        for (int P = 0; P < 4; ++P) {
            const int t = tbs + P;
            {   // prefetch xp(t+2) into buffer (P+2)&3
                int tl = (t + 2 < TT) ? (t + 2) : (TT - 1);
                int ta = dir ? (TT - 1 - tl) : tl;
                const half8_t* p0 = (const half8_t*)(xq0 + (size_t)ta * 8192);
                const half8_t* p1 = (const half8_t*)(xq1 + (size_t)ta * 8192);
                Q[(P + 2) & 3][0] = p0[0]; Q[(P + 2) & 3][1] = p0[1];
                Q[(P + 2) & 3][2] = p1[0]; Q[(P + 2) & 3][3] = p1[1];
            }

            half8_t bh[4];
            #pragma unroll
            for (int kk = 0; kk < 4; ++kk)
                bh[kk] = *(const half8_t*)&hsm[P & 1][lm * 136 + kk * 32 + lq * 8];

            // 32 MFMAs: 8 independent accumulator chains, shared B-fragment
            float4_t acc[4][2];
            #pragma unroll
            for (int T = 0; T < 4; ++T)
                #pragma unroll
                for (int p = 0; p < 2; ++p)
                    acc[T][p] = __builtin_amdgcn_mfma_f32_16x16x32_f16(awhh[T][p][0], bh[0], zz, 0, 0, 0);
            #pragma unroll
            for (int kk = 1; kk < 4; ++kk)
                #pragma unroll
                for (int T = 0; T < 4; ++T)
                    #pragma unroll
                    for (int p = 0; p < 2; ++p)
                        acc[T][p] = __builtin_amdgcn_mfma_f32_16x16x32_f16(awhh[T][p][kk], bh[kk], acc[T][p], 0, 0, 0);

            #pragma unroll
            for (int p = 0; p < 2; ++p) {
                half2_t qa0 = __builtin_shufflevector(Q[P][2 * p], Q[P][2 * p], 0, 1);
                half2_t qa1 = __builtin_shufflevector(Q[P][2 * p], Q[P][2 * p], 2, 3);
                half2_t qa2 = __builtin_shufflevector(Q[P][2 * p], Q[P][2 * p], 4, 5);
                half2_t qa3 = __builtin_shufflevector(Q[P][2 * p], Q[P][2 * p], 6, 7);
                half2_t qb0 = __builtin_shufflevector(Q[P][2 * p + 1], Q[P][2 * p + 1], 0, 1);
                half2_t qb1 = __builtin_shufflevector(Q[P][2 * p + 1], Q[P][2 * p + 1], 2, 3);
                half2_t qb2 = __builtin_shufflevector(Q[P][2 * p + 1], Q[P][2 * p + 1], 4, 5);
                half2_t qb3 = __builtin_shufflevector(Q[P][2 * p + 1], Q[P][2 * p + 1], 6, 7);

                half2_t i01 = sigma_pk(pkrtz(acc[0][p][0], acc[0][p][1]) + qa0);
                half2_t i23 = sigma_pk(pkrtz(acc[0][p][2], acc[0][p][3]) + qa1);
                half2_t f01 = sigma_pk(pkrtz(acc[1][p][0], acc[1][p][1]) + qa2);
                half2_t f23 = sigma_pk(pkrtz(acc[1][p][2], acc[1][p][3]) + qa3);
                half2_t g01 = tanh_pk(pkrtz(acc[2][p][0], acc[2][p][1]) + qb0);
                half2_t g23 = tanh_pk(pkrtz(acc[2][p][2], acc[2][p][3]) + qb1);
                half2_t o01 = sigma_pk(pkrtz(acc[3][p][0], acc[3][p][1]) + qb2);
                half2_t o23 = sigma_pk(pkrtz(acc[3][p][2], acc[3][p][3]) + qb3);

                c01[p] = f01 * c01[p] + i01 * g01;
                c23[p] = f23 * c23[p] + i23 * g23;
                half2_t h01 = o01 * tanh_pk(c01[p]);
                half2_t h23 = o23 * tanh_pk(c23[p]);
                hm01[p] = __builtin_elementwise_max(hm01[p], h01);
                hm23[p] = __builtin_elementwise_max(hm23[p], h23);

                half4_t hv4;
                hv4[0] = h01[0]; hv4[1] = h01[1]; hv4[2] = h23[0]; hv4[3] = h23[1];
                *(half4_t*)&hsm[1 - (P & 1)][lm * 136 + (2 * wv + p) * 16 + lq * 4] = hv4;
            }

            wg_barrier_lds();
        }
    }

    #pragma unroll
    for (int p = 0; p < 2; ++p) {
        float4 o;
        o.x = (float)hm01[p][0]; o.y = (float)hm01[p][1];
        o.z = (float)hm23[p][0]; o.w = (float)hm23[p][1];
        *(float4*)&pooled[(size_t)(bg * 16 + lm) * 256 + dir * HH + (2 * wv + p) * 16 + lq * 4] = o;
    }
}

// ---- kernel 3: pooled (128,256) -> relu(W1·+b1) -> sigmoid(W2·+b2) -> (128,1)
__global__ __launch_bounds__(64) void mlp_kernel(
    const float* __restrict__ pooled, const float* __restrict__ W1,
    const float* __restrict__ b1, const float* __restrict__ W2,
    const float* __restrict__ b2, float* __restrict__ out)
{
    const int b = blockIdx.x;
    const int j = threadIdx.x;
    const float4* p = (const float4*)(pooled + (size_t)b * 256);
    const float4* wv = (const float4*)(W1 + (size_t)j * 256);
    float s = 0.0f;
    #pragma unroll
    for (int q = 0; q < 64; ++q) {
        float4 pv = p[q];
        float4 ww = wv[q];
        s += pv.x * ww.x + pv.y * ww.y + pv.z * ww.z + pv.w * ww.w;
    }
    s += b1[j];
    s = fmaxf(s, 0.0f);
    float v = W2[j] * s;
    #pragma unroll
    for (int off = 32; off; off >>= 1) v += __shfl_down(v, off);
    if (j == 0) out[b] = 1.0f / (1.0f + __expf(-(v + b2[0])));
}

extern "C" void kernel_launch(void* const* d_in, const int* in_sizes, int n_in,
                              void* d_out, int out_size, void* d_ws, size_t ws_size,
                              hipStream_t stream) {
    const int*   x     = (const int*)d_in[0];
    const float* emb   = (const float*)d_in[1];
    const float* Wih_f = (const float*)d_in[2];
    const float* Whh_f = (const float*)d_in[3];
    const float* bih_f = (const float*)d_in[4];
    const float* bhh_f = (const float*)d_in[5];
    const float* Wih_b = (const float*)d_in[6];
    const float* Whh_b = (const float*)d_in[7];
    const float* bih_b = (const float*)d_in[8];
    const float* bhh_b = (const float*)d_in[9];
    const float* W1    = (const float*)d_in[10];
    const float* b1    = (const float*)d_in[11];
    const float* W2    = (const float*)d_in[12];
    const float* b2    = (const float*)d_in[13];
    float* out = (float*)d_out;

    char* ws = (char*)d_ws;
    float*    pooled = (float*)ws;                 // 128 KB
    _Float16* xp     = (_Float16*)(ws + 131072);   // 134.2 MB

    hipLaunchKernelGGL(xp_gemm_kernel, dim3(16, 32), dim3(512), 0, stream,
                       x, emb, Wih_f, bih_f, bhh_f, Wih_b, bih_b, bhh_b, xp);
    hipLaunchKernelGGL(bilstm_rec_kernel, dim3(16), dim3(256), 0, stream,
                       xp, Whh_f, Whh_b, pooled);
    hipLaunchKernelGGL(mlp_kernel, dim3(128), dim3(64), 0, stream,
                       pooled, W1, b1, W2, b2, out);
}

// Round 4
// 470.640 us; speedup vs baseline: 1.5547x; 1.1925x over previous
//
#include <hip/hip_runtime.h>
#include <hip/hip_fp16.h>

#define TT 512
#define HH 128

typedef _Float16 half2_t __attribute__((ext_vector_type(2)));
typedef _Float16 half4_t __attribute__((ext_vector_type(4)));
typedef _Float16 half8_t __attribute__((ext_vector_type(8)));
typedef float    float4_t __attribute__((ext_vector_type(4)));

__device__ __forceinline__ half2_t h2(float v) {
    half2_t r; r[0] = (_Float16)v; r[1] = (_Float16)v; return r;
}
__device__ __forceinline__ half2_t pkrtz(float a, float b) {
    return __builtin_bit_cast(half2_t, __builtin_amdgcn_cvt_pkrtz(a, b));
}

// ---- packed-f16 polynomial activations (no transcendentals) ----
#define TC1 0.994940f
#define TC3 -0.290799f
#define TC5 0.065507f
#define TC7 -0.0062464f
#define SC1 0.2487350f
#define SC3 -0.0181749f
#define SC5 0.00102355f
#define SC7 -0.0000244141f

__device__ __forceinline__ half2_t tanh_pk(half2_t x) {
    half2_t m = __builtin_elementwise_min(__builtin_elementwise_max(x, h2(-2.0f)), h2(2.0f));
    half2_t t = m * m;
    half2_t p = h2(TC7) * t + h2(TC5);
    p = p * t + h2(TC3);
    p = p * t + h2(TC1);
    return m * p;
}
__device__ __forceinline__ half2_t sigma_pk(half2_t x) {
    half2_t m = __builtin_elementwise_min(__builtin_elementwise_max(x, h2(-4.0f)), h2(4.0f));
    half2_t t = m * m;
    half2_t p = h2(SC7) * t + h2(SC5);
    p = p * t + h2(SC3);
    p = p * t + h2(SC1);
    return m * p + h2(0.5f);
}

// LDS-only barrier: waits lgkmcnt(0), leaves global loads/stores in flight.
__device__ __forceinline__ void wg_barrier_lds() {
#if __has_builtin(__builtin_amdgcn_s_waitcnt)
    __builtin_amdgcn_s_waitcnt(0xC07F);   // lgkmcnt(0), vmcnt=max, expcnt=max
#else
    asm volatile("s_waitcnt lgkmcnt(0)" ::: "memory");
#endif
    __builtin_amdgcn_s_barrier();
}

// xp layout (f16): half index = (((dirbg*512 + t)*8 + w)*64 + lane)*16,
// 16 halfs per (t,w,lane) in D-order [T*4+r]. Transposed MFMA convention:
// lane (lq,lm) holds gates T*128 + w*16 + lq*4 + r for chain bg*16+lm.
__device__ __forceinline__ size_t xp_off(int dirbg, int t, int w, int lane) {
    return (((size_t)dirbg * 512 + t) * 8 + w) * 1024 + (size_t)lane * 16;
}

// ---- kernel 1: block-staged xp GEMM (r11, proven ~67us). Unchanged.
__global__ __attribute__((amdgpu_flat_work_group_size(512, 512), amdgpu_waves_per_eu(2, 2)))
void xp_gemm_kernel(
    const int* __restrict__ x, const float* __restrict__ emb,
    const float* __restrict__ Wih_f, const float* __restrict__ bih_f, const float* __restrict__ bhh_f,
    const float* __restrict__ Wih_b, const float* __restrict__ bih_b, const float* __restrict__ bhh_b,
    _Float16* __restrict__ xp)
{
    const int wg  = blockIdx.x;        // dirbg
    const int dir = wg >> 3, bg = wg & 7;
    const int tb  = blockIdx.y * 16;   // t-base

    const float* Wih = dir ? Wih_b : Wih_f;
    const float* bih = dir ? bih_b : bih_f;
    const float* bhh = dir ? bhh_b : bhh_f;

    const int tid = threadIdx.x;
    const int w = tid >> 6, lane = tid & 63, lq = lane >> 4, lm = lane & 15;

    __shared__ int id_sm[256];                 // [chain][t]
    __shared__ _Float16 Esm[256 * 136];        // [t*16+chain][col], +8 pad

    if (tid < 256)
        id_sm[tid] = x[(size_t)(bg * 16 + (tid >> 4)) * TT + tb + (tid & 15)];

    half8_t awih[4][4];
    #pragma unroll
    for (int T = 0; T < 4; ++T) {
        #pragma unroll
        for (int kk = 0; kk < 4; ++kk) {
            const float4* s = (const float4*)(Wih + (size_t)(T * 128 + w * 16 + lm) * 128 + kk * 32 + lq * 8);
            float4 v0 = s[0], v1 = s[1];
            half8_t h;
            half2_t a = pkrtz(v0.x, v0.y), b = pkrtz(v0.z, v0.w);
            half2_t c = pkrtz(v1.x, v1.y), d = pkrtz(v1.z, v1.w);
            h[0]=a[0]; h[1]=a[1]; h[2]=b[0]; h[3]=b[1];
            h[4]=c[0]; h[5]=c[1]; h[6]=d[0]; h[7]=d[1];
            awih[T][kk] = h;
        }
    }
    float4_t biasv[4];
    #pragma unroll
    for (int T = 0; T < 4; ++T) {
        int g = T * 128 + w * 16 + lq * 4;
        float4 b1 = *(const float4*)(bih + g);
        float4 b2 = *(const float4*)(bhh + g);
        biasv[T] = (float4_t){b1.x + b2.x, b1.y + b2.y, b1.z + b2.z, b1.w + b2.w};
    }
    __syncthreads();   // id_sm ready

    {   // stage phase: 2 threads per (chain,t) row, 16 float4 each
        const int r  = tid >> 1;
        const int hf = tid & 1;
        const int chain = r >> 4, tt2 = r & 15;
        const float* src = emb + (size_t)id_sm[r] * 128 + hf * 64;
        float4 v[16];
        #pragma unroll
        for (int j = 0; j < 16; ++j) v[j] = *(const float4*)(src + 4 * j);
        _Float16* dst = &Esm[(tt2 * 16 + chain) * 136 + hf * 64];
        #pragma unroll
        for (int j = 0; j < 16; ++j) {
            half2_t a = pkrtz(v[j].x, v[j].y), b = pkrtz(v[j].z, v[j].w);
            half4_t q; q[0]=a[0]; q[1]=a[1]; q[2]=b[0]; q[3]=b[1];
            *(half4_t*)(dst + 4 * j) = q;
        }
    }
    __syncthreads();   // Esm ready; read-only below -> no more barriers

    #pragma unroll 4
    for (int i = 0; i < 16; ++i) {
        half8_t bfr[4];
        #pragma unroll
        for (int kk = 0; kk < 4; ++kk)
            bfr[kk] = *(const half8_t*)&Esm[(i * 16 + lm) * 136 + kk * 32 + lq * 8];

        float4_t acc[4];
        #pragma unroll
        for (int T = 0; T < 4; ++T) acc[T] = biasv[T];
        #pragma unroll
        for (int kk = 0; kk < 4; ++kk)
            #pragma unroll
            for (int T = 0; T < 4; ++T)
                acc[T] = __builtin_amdgcn_mfma_f32_16x16x32_f16(awih[T][kk], bfr[kk], acc[T], 0, 0, 0);

        half8_t p0, p1;
        {
            half2_t a = pkrtz(acc[0][0], acc[0][1]), b = pkrtz(acc[0][2], acc[0][3]);
            half2_t c = pkrtz(acc[1][0], acc[1][1]), d = pkrtz(acc[1][2], acc[1][3]);
            p0[0]=a[0]; p0[1]=a[1]; p0[2]=b[0]; p0[3]=b[1];
            p0[4]=c[0]; p0[5]=c[1]; p0[6]=d[0]; p0[7]=d[1];
        }
        {
            half2_t a = pkrtz(acc[2][0], acc[2][1]), b = pkrtz(acc[2][2], acc[2][3]);
            half2_t c = pkrtz(acc[3][0], acc[3][1]), d = pkrtz(acc[3][2], acc[3][3]);
            p1[0]=a[0]; p1[1]=a[1]; p1[2]=b[0]; p1[3]=b[1];
            p1[4]=c[0]; p1[5]=c[1]; p1[6]=d[0]; p1[7]=d[1];
        }
        half8_t* dst = (half8_t*)(xp + xp_off(wg, tb + i, w, lane));
        dst[0] = p0; dst[1] = p1;
    }
}

// ---- kernel 2: recurrence (r11 8-wave structure) with B-FRAGMENT-LINEAR hsm.
// r15 change: hsm is stored in MFMA B-operand order [buf][kk][lane][8 halfs]
// so each lane's bh[kk] read is base + lane*16B + kk*1024B -> per-lane-linear
// (the m134-optimal conflict-free pattern; one addr reg + imm offsets).
// The produce-side permutation moves to the b64 h-write (512B/wave/step,
// ~4-way, off the critical path). Old [chain][136] layout was a 4-way read
// conflict on 16 even banks (bank = 4(lm&7)+2lq) -> ~1.58x LDS phase cost.
__global__ __attribute__((amdgpu_flat_work_group_size(512, 512), amdgpu_waves_per_eu(2, 2)))
void bilstm_rec_kernel(
    const _Float16* __restrict__ xp,
    const float* __restrict__ Whh_f, const float* __restrict__ Whh_b,
    float* __restrict__ pooled)
{
    const int wg  = blockIdx.x;        // 0..15 dirbg
    const int dir = wg >> 3, bg = wg & 7;
    const float* Whh = dir ? Whh_b : Whh_f;

    const int tid = threadIdx.x;
    const int w = tid >> 6, lane = tid & 63, lq = lane >> 4, lm = lane & 15;

    __shared__ _Float16 hsm[2][2048];   // [buf][kk*512 + lane*8 + j] fragment-linear

    half8_t awhh[4][4];
    #pragma unroll
    for (int T = 0; T < 4; ++T) {
        #pragma unroll
        for (int kk = 0; kk < 4; ++kk) {
            const float4* s = (const float4*)(Whh + (size_t)(T * 128 + w * 16 + lm) * 128 + kk * 32 + lq * 8);
            float4 v0 = s[0], v1 = s[1];
            half8_t h;
            half2_t a = pkrtz(v0.x, v0.y), b = pkrtz(v0.z, v0.w);
            half2_t c = pkrtz(v1.x, v1.y), d = pkrtz(v1.z, v1.w);
            h[0]=a[0]; h[1]=a[1]; h[2]=b[0]; h[3]=b[1];
            h[4]=c[0]; h[5]=c[1]; h[6]=d[0]; h[7]=d[1];
            awhh[T][kk] = h;
        }
    }

    for (int k = tid; k < 2 * 2048; k += 512)
        ((_Float16*)hsm)[k] = (_Float16)0.0f;

    // read base: lane-linear; write base: fragment-order address of this
    // thread's 4 produced h values (dims w*16+lq*4.., chain lm) — both
    // step-invariant.
    const int rbase = lane * 8;
    const int wbase = (w >> 1) * 512 + ((w & 1) * 2 + (lq >> 1)) * 128 + lm * 8 + (lq & 1) * 4;

    const _Float16* xp_wl = xp + ((size_t)wg * 512 * 8 + w) * 1024 + (size_t)lane * 16;

    half8_t Qa[4], Qb[4];
    {
        int ta = dir ? (TT - 1) : 0;
        const half8_t* p = (const half8_t*)(xp_wl + (size_t)ta * 8192);
        Qa[0] = p[0]; Qb[0] = p[1];
    }
    {
        int ta = dir ? (TT - 2) : 1;
        const half8_t* p = (const half8_t*)(xp_wl + (size_t)ta * 8192);
        Qa[1] = p[0]; Qb[1] = p[1];
    }
    __syncthreads();

    const float4_t zz = {0.0f, 0.0f, 0.0f, 0.0f};   // persistent zero C-input
    half2_t c01 = h2(0.0f), c23 = h2(0.0f);
    half2_t hm01 = h2(-60000.0f), hm23 = h2(-60000.0f);

    for (int tbs = 0; tbs < TT; tbs += 4) {
        #pragma unroll
        for (int P = 0; P < 4; ++P) {
            const int t = tbs + P;
            {   // prefetch xp(t+2) into buffer (P+2)&3
                int tl = (t + 2 < TT) ? (t + 2) : (TT - 1);
                int ta = dir ? (TT - 1 - tl) : tl;
                const half8_t* pp = (const half8_t*)(xp_wl + (size_t)ta * 8192);
                Qa[(P + 2) & 3] = pp[0]; Qb[(P + 2) & 3] = pp[1];
            }

            const _Float16* hb = &hsm[P & 1][rbase];
            half8_t bh[4];
            bh[0] = *(const half8_t*)(hb + 0);
            bh[1] = *(const half8_t*)(hb + 512);
            bh[2] = *(const half8_t*)(hb + 1024);
            bh[3] = *(const half8_t*)(hb + 1536);

            // MFMA from zero-C; xp added post-MFMA in f16
            float4_t acc[4];
            #pragma unroll
            for (int T = 0; T < 4; ++T)
                acc[T] = __builtin_amdgcn_mfma_f32_16x16x32_f16(awhh[T][0], bh[0], zz, 0, 0, 0);
            #pragma unroll
            for (int kk = 1; kk < 4; ++kk)
                #pragma unroll
                for (int T = 0; T < 4; ++T)
                    acc[T] = __builtin_amdgcn_mfma_f32_16x16x32_f16(awhh[T][kk], bh[kk], acc[T], 0, 0, 0);

            // xp half2 views (alias Q's VGPRs; no conversion instructions)
            half2_t qa0 = __builtin_shufflevector(Qa[P], Qa[P], 0, 1);
            half2_t qa1 = __builtin_shufflevector(Qa[P], Qa[P], 2, 3);
            half2_t qa2 = __builtin_shufflevector(Qa[P], Qa[P], 4, 5);
            half2_t qa3 = __builtin_shufflevector(Qa[P], Qa[P], 6, 7);
            half2_t qb0 = __builtin_shufflevector(Qb[P], Qb[P], 0, 1);
            half2_t qb1 = __builtin_shufflevector(Qb[P], Qb[P], 2, 3);
            half2_t qb2 = __builtin_shufflevector(Qb[P], Qb[P], 4, 5);
            half2_t qb3 = __builtin_shufflevector(Qb[P], Qb[P], 6, 7);

            half2_t i01 = sigma_pk(pkrtz(acc[0][0], acc[0][1]) + qa0);
            half2_t i23 = sigma_pk(pkrtz(acc[0][2], acc[0][3]) + qa1);
            half2_t f01 = sigma_pk(pkrtz(acc[1][0], acc[1][1]) + qa2);
            half2_t f23 = sigma_pk(pkrtz(acc[1][2], acc[1][3]) + qa3);
            half2_t g01 = tanh_pk(pkrtz(acc[2][0], acc[2][1]) + qb0);
            half2_t g23 = tanh_pk(pkrtz(acc[2][2], acc[2][3]) + qb1);
            half2_t o01 = sigma_pk(pkrtz(acc[3][0], acc[3][1]) + qb2);
            half2_t o23 = sigma_pk(pkrtz(acc[3][2], acc[3][3]) + qb3);

            c01 = f01 * c01 + i01 * g01;
            c23 = f23 * c23 + i23 * g23;
            half2_t h01 = o01 * tanh_pk(c01);
            half2_t h23 = o23 * tanh_pk(c23);
            hm01 = __builtin_elementwise_max(hm01, h01);
            hm23 = __builtin_elementwise_max(hm23, h23);

            half4_t hv4;
            hv4[0] = h01[0]; hv4[1] = h01[1]; hv4[2] = h23[0]; hv4[3] = h23[1];
            *(half4_t*)&hsm[1 - (P & 1)][wbase] = hv4;

            wg_barrier_lds();
        }
    }

    float4 o;
    o.x = (float)hm01[0]; o.y = (float)hm01[1];
    o.z = (float)hm23[0]; o.w = (float)hm23[1];
    *(float4*)&pooled[(size_t)(bg * 16 + lm) * 256 + dir * HH + w * 16 + lq * 4] = o;
}

// ---- kernel 3: pooled (128,256) -> relu(W1·+b1) -> sigmoid(W2·+b2) -> (128,1)
__global__ __launch_bounds__(64) void mlp_kernel(
    const float* __restrict__ pooled, const float* __restrict__ W1,
    const float* __restrict__ b1, const float* __restrict__ W2,
    const float* __restrict__ b2, float* __restrict__ out)
{
    const int b = blockIdx.x;
    const int j = threadIdx.x;
    const float4* p = (const float4*)(pooled + (size_t)b * 256);
    const float4* wv = (const float4*)(W1 + (size_t)j * 256);
    float s = 0.0f;
    #pragma unroll
    for (int q = 0; q < 64; ++q) {
        float4 pv = p[q];
        float4 ww = wv[q];
        s += pv.x * ww.x + pv.y * ww.y + pv.z * ww.z + pv.w * ww.w;
    }
    s += b1[j];
    s = fmaxf(s, 0.0f);
    float v = W2[j] * s;
    #pragma unroll
    for (int off = 32; off; off >>= 1) v += __shfl_down(v, off);
    if (j == 0) out[b] = 1.0f / (1.0f + __expf(-(v + b2[0])));
}

extern "C" void kernel_launch(void* const* d_in, const int* in_sizes, int n_in,
                              void* d_out, int out_size, void* d_ws, size_t ws_size,
                              hipStream_t stream) {
    const int*   x     = (const int*)d_in[0];
    const float* emb   = (const float*)d_in[1];
    const float* Wih_f = (const float*)d_in[2];
    const float* Whh_f = (const float*)d_in[3];
    const float* bih_f = (const float*)d_in[4];
    const float* bhh_f = (const float*)d_in[5];
    const float* Wih_b = (const float*)d_in[6];
    const float* Whh_b = (const float*)d_in[7];
    const float* bih_b = (const float*)d_in[8];
    const float* bhh_b = (const float*)d_in[9];
    const float* W1    = (const float*)d_in[10];
    const float* b1    = (const float*)d_in[11];
    const float* W2    = (const float*)d_in[12];
    const float* b2    = (const float*)d_in[13];
    float* out = (float*)d_out;

    char* ws = (char*)d_ws;
    float*    pooled = (float*)ws;                 // 128 KB
    _Float16* xp     = (_Float16*)(ws + 131072);   // 134.2 MB

    hipLaunchKernelGGL(xp_gemm_kernel, dim3(16, 32), dim3(512), 0, stream,
                       x, emb, Wih_f, bih_f, bhh_f, Wih_b, bih_b, bhh_b, xp);
    hipLaunchKernelGGL(bilstm_rec_kernel, dim3(16), dim3(512), 0, stream,
                       xp, Whh_f, Whh_b, pooled);
    hipLaunchKernelGGL(mlp_kernel, dim3(128), dim3(64), 0, stream,
                       pooled, W1, b1, W2, b2, out);
}